// Round 19
// baseline (1349.463 us; speedup 1.0000x reference)
//
#include <hip/hip_runtime.h>
#include <hip/hip_fp16.h>
#include <math.h>

// ---------------------------------------------------------------------------
// GATv2 x2 + mean-pool + linear, MI355X.
// R19: persistent single-kernel with MANUAL grid barriers (classic device
//      atomics + s_sleep spin; R12's hipLaunchCooperativeKernel failed
//      silently). Residency proof: 1024 blocks = 256 CU x 4;
//      __launch_bounds__(256,4) caps VGPR 128; 8KB LDS/block -> 32KB/CU.
//      All blocks co-resident => barrier progress guaranteed.
//      ~75us of R18's 248 was dispatch boundaries; this removes 5 of 6.
//      Phases: fill+gemm1 | agg1 | gemm2 | agg2 | pool | final.
// ---------------------------------------------------------------------------

#define ELLC    48
#define OVF_CAP 65536
#define ECHUNK  2048
#define GROWS   32
#define NBLK    1024
#define FILLB   688           // fill-role blocks in P1 (688 % 8 == 0 -> keeps vb&7)

typedef int      vint4 __attribute__((ext_vector_type(4)));
typedef _Float16 half4 __attribute__((ext_vector_type(4)));

// ---------------- manual grid barrier (all blocks resident) ----------------
__device__ __forceinline__ void grid_barrier(int* bar, int& gen) {
    __threadfence();               // publish this block's writes (device scope)
    __syncthreads();
    if (threadIdx.x == 0) {
        int arrived = atomicAdd(&bar[0], 1);          // device-scope RMW
        if (arrived == NBLK - 1) {
            atomicExch(&bar[0], 0);                   // reset for next use
            __threadfence();
            atomicExch(&bar[1], gen + 1);             // release
        } else {
            while (atomicAdd(&bar[1], 0) != gen + 1)  // RMW read, device scope
                __builtin_amdgcn_s_sleep(8);
        }
    }
    gen++;
    __syncthreads();
    __threadfence();               // acquire side
}

// ---------------- slim dual GEMM body: xl = X*Wl + bl (fp16), xr = X*Wr + br
template <typename T>
__device__ __forceinline__ void dual_gemm_slim(
    int bid, int t,
    const T* __restrict__ X,
    const float* __restrict__ Wl, const float* __restrict__ bl,
    const float* __restrict__ Wr, const float* __restrict__ br,
    _Float16* __restrict__ xl, float* __restrict__ xr, int n,
    float* xS) {
    int row0 = bid * GROWS;
    for (int i = t; i < GROWS * 16; i += 256) {
        int r = row0 + (i >> 4);
        float4 v = make_float4(0.f, 0.f, 0.f, 0.f);
        if (r < n) {
            if constexpr (sizeof(T) == 2) {
                half4 hv = ((const half4*)(X + (size_t)r * 64))[i & 15];
                v = make_float4((float)hv[0], (float)hv[1], (float)hv[2], (float)hv[3]);
            } else {
                v = ((const float4*)(X + (size_t)r * 64))[i & 15];
            }
        }
        ((float4*)xS)[i] = v;
    }
    __syncthreads();
    int h  = t & 63;
    int rb = t >> 6;
    float accl[8], accr[8];
#pragma unroll
    for (int i = 0; i < 8; ++i) { accl[i] = 0.f; accr[i] = 0.f; }
#pragma unroll 4
    for (int d = 0; d < 64; ++d) {
        float wl = Wl[d * 64 + h];   // coalesced 256B, L2-hot
        float wr = Wr[d * 64 + h];
#pragma unroll
        for (int i = 0; i < 8; ++i) {
            float xv = xS[(rb + 4 * i) * 64 + d];
            accl[i] += xv * wl;
            accr[i] += xv * wr;
        }
    }
    float blv = bl[h], brv = br[h];
#pragma unroll
    for (int i = 0; i < 8; ++i) {
        int r = row0 + rb + 4 * i;
        if (r < n) {
            xl[(size_t)r * 64 + h] = (_Float16)(accl[i] + blv);
            xr[(size_t)r * 64 + h] = accr[i] + brv;
        }
    }
    __syncthreads();   // xS safe to re-stage on next loop iteration
}

// ---------------- XCD-partitioned ELL fill chunk ----------------
__device__ __forceinline__ void fill_chunk(
    int vb, int t,
    const int* __restrict__ src, const int* __restrict__ dst,
    int* __restrict__ cnt, unsigned short* __restrict__ ell,
    int* __restrict__ novf, int* __restrict__ ovf_dst, int* __restrict__ ovf_src,
    int E, int N, int psize) {
    int chunk = vb >> 3;
    int p     = vb & 7;                   // partition == XCD (round-robin)
    int d0    = p * psize;
    int d1    = min(N, d0 + psize);
    int e0    = chunk * ECHUNK;
    int e1    = min(E, e0 + ECHUNK);
    int nq    = (e1 - e0) >> 2;
    const vint4* dst4 = (const vint4*)(dst + e0);
    const vint4* src4 = (const vint4*)(src + e0);

    auto scatter4 = [&](vint4 dv, vint4 sv) {
#pragma unroll
        for (int k = 0; k < 4; ++k) {
            int d = dv[k];
            int s = sv[k];
            if (d >= d0 && d < d1) {
                int pos = atomicAdd(&cnt[d], 1);
                if (pos < ELLC) {
                    ell[d * ELLC + pos] = (unsigned short)s;
                } else {  // P(deg>48) ~ 5e-11 per node
                    int j = atomicAdd(novf, 1);
                    if (j < OVF_CAP) { ovf_dst[j] = d; ovf_src[j] = s; }
                }
            }
        }
    };

    if (nq == (ECHUNK >> 2)) {
        vint4 dvA = __builtin_nontemporal_load(&dst4[t]);
        vint4 svA = __builtin_nontemporal_load(&src4[t]);
        vint4 dvB = __builtin_nontemporal_load(&dst4[t + 256]);
        vint4 svB = __builtin_nontemporal_load(&src4[t + 256]);
        scatter4(dvA, svA);
        scatter4(dvB, svB);
    } else {
        for (int qq = t; qq < nq; qq += 256) {
            vint4 dv = __builtin_nontemporal_load(&dst4[qq]);
            vint4 sv = __builtin_nontemporal_load(&src4[qq]);
            scatter4(dv, sv);
        }
        for (int e = e0 + (nq << 2) + t; e < e1; e += 256) {
            int d = dst[e];
            if (d >= d0 && d < d1) {
                int pos = atomicAdd(&cnt[d], 1);
                int s   = src[e];
                if (pos < ELLC) {
                    ell[d * ELLC + pos] = (unsigned short)s;
                } else {
                    int j = atomicAdd(novf, 1);
                    if (j < OVF_CAP) { ovf_dst[j] = d; ovf_src[j] = s; }
                }
            }
        }
    }
}

// ---------------- per-dst GATv2 aggregation (one node) --------------------
__device__ __forceinline__ void agg_node(
    int d, int lane,
    const _Float16* __restrict__ xl, const float* __restrict__ xr,
    const int* __restrict__ cnt, const unsigned short* __restrict__ ell,
    const int* __restrict__ novf, const int* __restrict__ ovf_dst,
    const int* __restrict__ ovf_src,
    const float* __restrict__ att, const float* __restrict__ bias,
    _Float16* __restrict__ out) {
    int g = lane >> 4;   // slot group
    int l = lane & 15;   // feature quad
    float4 att4 = ((const float4*)att)[l];
    float4 b4   = ((const float4*)bias)[l];
    int deg_d = cnt[d];
    int nd  = min(deg_d, ELLC);
    int beg = d * ELLC;

    float  s   = 0.f;
    float4 acc = make_float4(0.f, 0.f, 0.f, 0.f);

    if (deg_d > 0) {
        int myidx = 0;
        if (lane < ELLC) myidx = (int)ell[beg + lane];   // one 96B row read
        int i_first = __shfl(myidx, 0);

        float4 xr4 = ((const float4*)(xr + (size_t)d * 64))[l];

#pragma unroll 6
        for (int k = 0; k * 8 < nd; ++k) {     // k < 6 (nd <= 48); uniform
            int  sa = k * 8 + g, sb = sa + 4;
            bool aa = sa < nd,   ab = sb < nd;
            int  i0 = __shfl(myidx, sa); if (!aa) i0 = i_first;
            int  i1 = __shfl(myidx, sb); if (!ab) i1 = i_first;
            half4 h0 = ((const half4*)(xl + (size_t)i0 * 64))[l];  // 8B gather
            half4 h1 = ((const half4*)(xl + (size_t)i1 * 64))[l];
            float4 x0 = make_float4((float)h0[0], (float)h0[1], (float)h0[2], (float)h0[3]);
            float4 x1 = make_float4((float)h1[0], (float)h1[1], (float)h1[2], (float)h1[3]);
            float z, c0 = 0.f, c1 = 0.f;
            z = x0.x + xr4.x; c0 += ((z > 0.f) ? z : 0.2f * z) * att4.x;
            z = x0.y + xr4.y; c0 += ((z > 0.f) ? z : 0.2f * z) * att4.y;
            z = x0.z + xr4.z; c0 += ((z > 0.f) ? z : 0.2f * z) * att4.z;
            z = x0.w + xr4.w; c0 += ((z > 0.f) ? z : 0.2f * z) * att4.w;
            z = x1.x + xr4.x; c1 += ((z > 0.f) ? z : 0.2f * z) * att4.x;
            z = x1.y + xr4.y; c1 += ((z > 0.f) ? z : 0.2f * z) * att4.y;
            z = x1.z + xr4.z; c1 += ((z > 0.f) ? z : 0.2f * z) * att4.z;
            z = x1.w + xr4.w; c1 += ((z > 0.f) ? z : 0.2f * z) * att4.w;
#pragma unroll
            for (int sh = 8; sh >= 1; sh >>= 1) {  // 16-lane reduce
                c0 += __shfl_xor(c0, sh);
                c1 += __shfl_xor(c1, sh);
            }
            float w0 = aa ? __expf(fminf(c0, 30.f)) : 0.f;
            float w1 = ab ? __expf(fminf(c1, 30.f)) : 0.f;
            s += w0 + w1;
            acc.x += w0 * x0.x + w1 * x1.x;
            acc.y += w0 * x0.y + w1 * x1.y;
            acc.z += w0 * x0.z + w1 * x1.z;
            acc.w += w0 * x0.w + w1 * x1.w;
        }
        if (deg_d > ELLC) {   // overflow fold; empty in practice
            int no = min(*novf, OVF_CAP);
            for (int j = g; j < no; j += 4) {
                bool active = (ovf_dst[j] == d);
                int  i0     = active ? ovf_src[j] : i_first;
                half4 h0 = ((const half4*)(xl + (size_t)i0 * 64))[l];
                float4 x0 = make_float4((float)h0[0], (float)h0[1], (float)h0[2], (float)h0[3]);
                float z, c0 = 0.f;
                z = x0.x + xr4.x; c0 += ((z > 0.f) ? z : 0.2f * z) * att4.x;
                z = x0.y + xr4.y; c0 += ((z > 0.f) ? z : 0.2f * z) * att4.y;
                z = x0.z + xr4.z; c0 += ((z > 0.f) ? z : 0.2f * z) * att4.z;
                z = x0.w + xr4.w; c0 += ((z > 0.f) ? z : 0.2f * z) * att4.w;
#pragma unroll
                for (int sh = 8; sh >= 1; sh >>= 1) c0 += __shfl_xor(c0, sh);
                float w0 = active ? __expf(fminf(c0, 30.f)) : 0.f;
                s += w0;
                acc.x += w0 * x0.x;
                acc.y += w0 * x0.y;
                acc.z += w0 * x0.z;
                acc.w += w0 * x0.w;
            }
        }
#pragma unroll
        for (int mask = 16; mask <= 32; mask <<= 1) {
            s     += __shfl_xor(s, mask);
            acc.x += __shfl_xor(acc.x, mask);
            acc.y += __shfl_xor(acc.y, mask);
            acc.z += __shfl_xor(acc.z, mask);
            acc.w += __shfl_xor(acc.w, mask);
        }
    }
    if (g == 0) {
        float inv = (s > 0.f) ? (1.f / s) : 0.f;   // deg-0 -> relu(bias)
        half4 hv;
        hv[0] = (_Float16)fmaxf(acc.x * inv + b4.x, 0.f);
        hv[1] = (_Float16)fmaxf(acc.y * inv + b4.y, 0.f);
        hv[2] = (_Float16)fmaxf(acc.z * inv + b4.z, 0.f);
        hv[3] = (_Float16)fmaxf(acc.w * inv + b4.w, 0.f);
        ((half4*)(out + (size_t)d * 64))[l] = hv;
    }
}

// ---------------- the persistent mega kernel ----------------
__global__ __launch_bounds__(256, 4) void mega_kernel(
    const float* __restrict__ x,
    const int* __restrict__ src, const int* __restrict__ dst,
    const int* __restrict__ batch,
    const float* __restrict__ Wl1, const float* __restrict__ bl1,
    const float* __restrict__ Wr1, const float* __restrict__ br1,
    const float* __restrict__ att1, const float* __restrict__ bias1,
    const float* __restrict__ Wl2, const float* __restrict__ bl2,
    const float* __restrict__ Wr2, const float* __restrict__ br2,
    const float* __restrict__ att2, const float* __restrict__ bias2,
    const float* __restrict__ lin_w, const float* __restrict__ lin_b,
    float* __restrict__ out,
    _Float16* __restrict__ xl, float* __restrict__ xr, _Float16* __restrict__ h1,
    int* __restrict__ cnt, int* __restrict__ novf,
    float* __restrict__ sums, float* __restrict__ cnts,
    unsigned short* __restrict__ ell,
    int* __restrict__ ovf_dst, int* __restrict__ ovf_src, int* __restrict__ bar,
    int N, int E, int G, int fb, int ggrid, int psize) {
    __shared__ float xS[GROWS * 64];
    int bid  = blockIdx.x, t = threadIdx.x;
    int gen  = 0;
    int gw   = (bid << 2) + (t >> 6);     // global wave id, 0..4095
    int lane = t & 63;

    // ---- P1: ELL fill (blocks 0..FILLB-1) + layer-1 dual GEMM (rest) ----
    if (bid < FILLB) {
        for (int vb = bid; vb < fb; vb += FILLB)   // FILLB%8==0: vb&7 == bid&7
            fill_chunk(vb, t, src, dst, cnt, ell, novf, ovf_dst, ovf_src,
                       E, N, psize);
    } else {
        for (int vg = bid - FILLB; vg < ggrid; vg += NBLK - FILLB)
            dual_gemm_slim<float>(vg, t, x, Wl1, bl1, Wr1, br1, xl, xr, N, xS);
    }
    grid_barrier(bar, gen);

    // ---- P2: aggregate layer 1 -> h1 (fp16) ----
    for (int d = gw; d < N; d += NBLK * 4)
        agg_node(d, lane, xl, xr, cnt, ell, novf, ovf_dst, ovf_src,
                 att1, bias1, h1);
    grid_barrier(bar, gen);

    // ---- P3: layer-2 dual GEMM (fp16 input) ----
    for (int vg = bid; vg < ggrid; vg += NBLK)
        dual_gemm_slim<_Float16>(vg, t, h1, Wl2, bl2, Wr2, br2, xl, xr, N, xS);
    grid_barrier(bar, gen);

    // ---- P4: aggregate layer 2 -> h1 (fp16, reused) ----
    for (int d = gw; d < N; d += NBLK * 4)
        agg_node(d, lane, xl, xr, cnt, ell, novf, ovf_dst, ovf_src,
                 att2, bias2, h1);
    grid_barrier(bar, gen);

    // ---- P5: mean pool (run-length over sorted batch) ----
    {
        const int nwaves = NBLK * 4;
        int per   = (N + nwaves - 1) / nwaves;
        int start = gw * per;
        int end   = min(N, start + per);
        if (start < end) {
            int cur = batch[start];
            float acc = 0.f, c = 0.f;
            for (int i = start; i < end; ++i) {
                int gg = batch[i];   // wave-uniform
                if (gg != cur) {
                    atomicAdd(&sums[cur * 64 + lane], acc);
                    if (lane == 0) atomicAdd(&cnts[cur], c);
                    acc = 0.f; c = 0.f; cur = gg;
                }
                acc += (float)h1[(size_t)i * 64 + lane];
                c += 1.f;
            }
            atomicAdd(&sums[cur * 64 + lane], acc);
            if (lane == 0) atomicAdd(&cnts[cur], c);
        }
    }
    grid_barrier(bar, gen);

    // ---- P6: final linear ----
    int gtid = bid * 256 + t;
    if (gtid < G * 32) {
        int g = gtid >> 5, o = gtid & 31;
        float inv = 1.f / fmaxf(cnts[g], 1.f);
        float a = 0.f;
#pragma unroll 8
        for (int hh = 0; hh < 64; ++hh)
            a += sums[g * 64 + hh] * lin_w[hh * 32 + o];
        out[gtid] = a * inv + lin_b[o];
    }
}

extern "C" void kernel_launch(void* const* d_in, const int* in_sizes, int n_in,
                              void* d_out, int out_size, void* d_ws, size_t ws_size,
                              hipStream_t stream) {
    const float* x     = (const float*)d_in[0];
    const int*   ei    = (const int*)d_in[1];
    const int*   batch = (const int*)d_in[2];
    const float* Wl1   = (const float*)d_in[3];
    const float* bl1   = (const float*)d_in[4];
    const float* Wr1   = (const float*)d_in[5];
    const float* br1   = (const float*)d_in[6];
    const float* att1  = (const float*)d_in[7];
    const float* bias1 = (const float*)d_in[8];
    const float* Wl2   = (const float*)d_in[9];
    const float* bl2   = (const float*)d_in[10];
    const float* Wr2   = (const float*)d_in[11];
    const float* br2   = (const float*)d_in[12];
    const float* att2  = (const float*)d_in[13];
    const float* bias2 = (const float*)d_in[14];
    const float* lin_w = (const float*)d_in[15];
    const float* lin_b = (const float*)d_in[16];
    float* out = (float*)d_out;

    const int N = in_sizes[0] / 64;
    const int E = in_sizes[1] / 2;
    const int G = out_size / 32;
    const int* src = ei;
    const int* dst = ei + E;

    // ---- workspace carve-up (256B-aligned) ----
    char*  ws  = (char*)d_ws;
    size_t off = 0;
    auto alloc = [&](size_t bytes) -> void* {
        void* p = ws + off;
        off += bytes;
        off = (off + 255) & ~(size_t)255;
        return p;
    };
    _Float16* xl   = (_Float16*)alloc((size_t)N * 64 * sizeof(_Float16));
    float* xr      = (float*)alloc((size_t)N * 64 * sizeof(float));
    _Float16* h1   = (_Float16*)alloc((size_t)N * 64 * sizeof(_Float16));
    // zeroed region (contiguous): cnt, novf, bar, sums, cnts
    int*   cnt     = (int*)alloc((size_t)N * sizeof(int));
    int*   novf    = (int*)alloc(256);
    int*   bar     = (int*)alloc(256);
    float* sums    = (float*)alloc((size_t)G * 64 * sizeof(float));
    float* cnts    = (float*)alloc((size_t)G * sizeof(float));
    char*  zend    = ws + off;
    unsigned short* ell = (unsigned short*)alloc((size_t)N * ELLC * sizeof(unsigned short));
    int*   ovf_dst = (int*)alloc((size_t)OVF_CAP * sizeof(int));
    int*   ovf_src = (int*)alloc((size_t)OVF_CAP * sizeof(int));

    (void)hipMemsetAsync(cnt, 0, (size_t)(zend - (char*)cnt), stream);

    int ggrid  = (N + GROWS - 1) / GROWS;
    int nchunk = (E + ECHUNK - 1) / ECHUNK;
    int fb     = nchunk * 8;            // fill virtual blocks (x8 XCD copies)
    int psize  = (N + 7) / 8;

    mega_kernel<<<NBLK, 256, 0, stream>>>(
        x, src, dst, batch,
        Wl1, bl1, Wr1, br1, att1, bias1,
        Wl2, bl2, Wr2, br2, att2, bias2,
        lin_w, lin_b, out,
        xl, xr, h1, cnt, novf, sums, cnts, ell, ovf_dst, ovf_src, bar,
        N, E, G, fb, ggrid, psize);
}

// Round 20
// 243.412 us; speedup vs baseline: 5.5440x; 5.5440x over previous
//
#include <hip/hip_runtime.h>
#include <hip/hip_fp16.h>
#include <math.h>

// ---------------------------------------------------------------------------
// GATv2 x2 + mean-pool + linear, MI355X.
// R20: revert R19's spin-barrier persistent kernel (1277us: 1023 blocks
//      spinning device-scope RMW on ONE line = cross-XCD coherence storm).
//      Grid-sync is 0-for-2 on this harness -> accept dispatch boundaries.
//      Base = R18 (248us) + pool/final merged into a per-graph block kernel
//      (512 blocks, binary-search sorted batch, zero atomics, no sums memset).
// ---------------------------------------------------------------------------

#define ELLC    48
#define OVF_CAP 65536
#define ECHUNK  2048          // edges per fill virtual block

typedef int      vint4 __attribute__((ext_vector_type(4)));
typedef _Float16 half4 __attribute__((ext_vector_type(4)));

// ---------------- slim dual GEMM body: xl = X*Wl + bl (fp16), xr = X*Wr + br
#define GROWS 32
template <typename T>
__device__ __forceinline__ void dual_gemm_slim(
    int bid, int t,
    const T* __restrict__ X,
    const float* __restrict__ Wl, const float* __restrict__ bl,
    const float* __restrict__ Wr, const float* __restrict__ br,
    _Float16* __restrict__ xl, float* __restrict__ xr, int n,
    float* xS) {
    int row0 = bid * GROWS;
    for (int i = t; i < GROWS * 16; i += 256) {
        int r = row0 + (i >> 4);
        float4 v = make_float4(0.f, 0.f, 0.f, 0.f);
        if (r < n) {
            if constexpr (sizeof(T) == 2) {
                half4 hv = ((const half4*)(X + (size_t)r * 64))[i & 15];
                v = make_float4((float)hv[0], (float)hv[1], (float)hv[2], (float)hv[3]);
            } else {
                v = ((const float4*)(X + (size_t)r * 64))[i & 15];
            }
        }
        ((float4*)xS)[i] = v;
    }
    __syncthreads();
    int h  = t & 63;
    int rb = t >> 6;  // 0..3
    float accl[8], accr[8];
#pragma unroll
    for (int i = 0; i < 8; ++i) { accl[i] = 0.f; accr[i] = 0.f; }
#pragma unroll 4
    for (int d = 0; d < 64; ++d) {
        float wl = Wl[d * 64 + h];   // coalesced 256B, L2-hot
        float wr = Wr[d * 64 + h];
#pragma unroll
        for (int i = 0; i < 8; ++i) {
            float xv = xS[(rb + 4 * i) * 64 + d];  // wave-uniform broadcast
            accl[i] += xv * wl;
            accr[i] += xv * wr;
        }
    }
    float blv = bl[h], brv = br[h];
#pragma unroll
    for (int i = 0; i < 8; ++i) {
        int r = row0 + rb + 4 * i;
        if (r < n) {
            xl[(size_t)r * 64 + h] = (_Float16)(accl[i] + blv);  // 2B, coalesced
            xr[(size_t)r * 64 + h] = accr[i] + brv;
        }
    }
}

__global__ __launch_bounds__(256) void dual_gemm64_f16_kernel(
    const _Float16* __restrict__ X,
    const float* __restrict__ Wl, const float* __restrict__ bl,
    const float* __restrict__ Wr, const float* __restrict__ br,
    _Float16* __restrict__ xl, float* __restrict__ xr, int n) {
    __shared__ float xS[GROWS * 64];
    dual_gemm_slim<_Float16>(blockIdx.x, threadIdx.x, X, Wl, bl, Wr, br,
                             xl, xr, n, xS);
}

// ---------------- interleaved: XCD-partitioned ELL fill + layer-1 GEMM ----
// 24-block groups: r = b%24. r<16 -> fill vb = (b/24)*16+r (vb&7 == b&7!);
// r>=16 -> gemm vg = (b/24)*8 + (r-16).
__global__ __launch_bounds__(256) void fill_gemm_kernel(
    const int* __restrict__ src, const int* __restrict__ dst,
    int* __restrict__ cnt, unsigned short* __restrict__ ell,
    int* __restrict__ novf, int* __restrict__ ovf_dst, int* __restrict__ ovf_src,
    int E, int N, int psize, int fb, int ggrid,
    const float* __restrict__ X,
    const float* __restrict__ Wl, const float* __restrict__ bl,
    const float* __restrict__ Wr, const float* __restrict__ br,
    _Float16* __restrict__ xl, float* __restrict__ xr) {
    __shared__ float xS[GROWS * 64];
    int b = blockIdx.x;
    int q = b / 24, r = b % 24;
    if (r >= 16) {
        int vg = q * 8 + (r - 16);
        if (vg < ggrid)
            dual_gemm_slim<float>(vg, threadIdx.x, X, Wl, bl, Wr, br,
                                  xl, xr, N, xS);
        return;
    }
    int vb = q * 16 + r;
    if (vb >= fb) return;
    int t     = threadIdx.x;
    int chunk = vb >> 3;
    int p     = vb & 7;                   // partition == XCD (== b&7)
    int d0    = p * psize;
    int d1    = min(N, d0 + psize);
    int e0    = chunk * ECHUNK;
    int e1    = min(E, e0 + ECHUNK);
    int nq    = (e1 - e0) >> 2;
    const vint4* dst4 = (const vint4*)(dst + e0);
    const vint4* src4 = (const vint4*)(src + e0);

    auto scatter4 = [&](vint4 dv, vint4 sv) {
#pragma unroll
        for (int k = 0; k < 4; ++k) {
            int d = dv[k];
            int s = sv[k];
            if (d >= d0 && d < d1) {
                int pos = atomicAdd(&cnt[d], 1);
                if (pos < ELLC) {
                    ell[d * ELLC + pos] = (unsigned short)s;
                } else {  // P(deg>48) ~ 5e-11 per node
                    int j = atomicAdd(novf, 1);
                    if (j < OVF_CAP) { ovf_dst[j] = d; ovf_src[j] = s; }
                }
            }
        }
    };

    if (nq == (ECHUNK >> 2)) {   // full chunk: both loads up front, 8 chains
        vint4 dvA = __builtin_nontemporal_load(&dst4[t]);
        vint4 svA = __builtin_nontemporal_load(&src4[t]);
        vint4 dvB = __builtin_nontemporal_load(&dst4[t + 256]);
        vint4 svB = __builtin_nontemporal_load(&src4[t + 256]);
        scatter4(dvA, svA);
        scatter4(dvB, svB);
    } else {
        for (int qq = t; qq < nq; qq += 256) {
            vint4 dv = __builtin_nontemporal_load(&dst4[qq]);
            vint4 sv = __builtin_nontemporal_load(&src4[qq]);
            scatter4(dv, sv);
        }
        for (int e = e0 + (nq << 2) + t; e < e1; e += 256) {  // E % 4 tail
            int d = dst[e];
            if (d >= d0 && d < d1) {
                int pos = atomicAdd(&cnt[d], 1);
                int s   = src[e];
                if (pos < ELLC) {
                    ell[d * ELLC + pos] = (unsigned short)s;
                } else {
                    int j = atomicAdd(novf, 1);
                    if (j < OVF_CAP) { ovf_dst[j] = d; ovf_src[j] = s; }
                }
            }
        }
    }
}

// ---------------- per-dst GATv2 aggregation (one wave per dst) ------------
// wave = 4 groups x 16 lanes; ELL row preloaded once, indices via __shfl.
// Output: fp16 h row.
__global__ __launch_bounds__(256) void gat_aggregate_kernel(
    const _Float16* __restrict__ xl, const float* __restrict__ xr,
    const int* __restrict__ cnt, const unsigned short* __restrict__ ell,
    const int* __restrict__ novf, const int* __restrict__ ovf_dst,
    const int* __restrict__ ovf_src,
    const float* __restrict__ att, const float* __restrict__ bias,
    _Float16* __restrict__ out, int n) {
    int wid  = (blockIdx.x * blockDim.x + threadIdx.x) >> 6;
    int lane = threadIdx.x & 63;
    if (wid >= n) return;
    int g = lane >> 4;   // slot group
    int l = lane & 15;   // feature quad
    int d = wid;

    float4 att4 = ((const float4*)att)[l];
    float4 b4   = ((const float4*)bias)[l];
    int deg_d = cnt[d];
    int nd  = min(deg_d, ELLC);
    int beg = d * ELLC;

    float  s   = 0.f;
    float4 acc = make_float4(0.f, 0.f, 0.f, 0.f);

    if (deg_d > 0) {
        // one coalesced 96B read of the whole ELL row; lane i holds slot i
        int myidx = 0;
        if (lane < ELLC) myidx = (int)ell[beg + lane];
        int i_first = __shfl(myidx, 0);

        float4 xr4 = ((const float4*)(xr + (size_t)d * 64))[l];

#pragma unroll 6
        for (int k = 0; k * 8 < nd; ++k) {     // k < 6 (nd <= 48); uniform
            int  sa = k * 8 + g, sb = sa + 4;
            bool aa = sa < nd,   ab = sb < nd;
            int  i0 = __shfl(myidx, sa); if (!aa) i0 = i_first;
            int  i1 = __shfl(myidx, sb); if (!ab) i1 = i_first;
            half4 h0 = ((const half4*)(xl + (size_t)i0 * 64))[l];  // 8B gather
            half4 h1 = ((const half4*)(xl + (size_t)i1 * 64))[l];
            float4 x0 = make_float4((float)h0[0], (float)h0[1], (float)h0[2], (float)h0[3]);
            float4 x1 = make_float4((float)h1[0], (float)h1[1], (float)h1[2], (float)h1[3]);
            float z, c0 = 0.f, c1 = 0.f;
            z = x0.x + xr4.x; c0 += ((z > 0.f) ? z : 0.2f * z) * att4.x;
            z = x0.y + xr4.y; c0 += ((z > 0.f) ? z : 0.2f * z) * att4.y;
            z = x0.z + xr4.z; c0 += ((z > 0.f) ? z : 0.2f * z) * att4.z;
            z = x0.w + xr4.w; c0 += ((z > 0.f) ? z : 0.2f * z) * att4.w;
            z = x1.x + xr4.x; c1 += ((z > 0.f) ? z : 0.2f * z) * att4.x;
            z = x1.y + xr4.y; c1 += ((z > 0.f) ? z : 0.2f * z) * att4.y;
            z = x1.z + xr4.z; c1 += ((z > 0.f) ? z : 0.2f * z) * att4.z;
            z = x1.w + xr4.w; c1 += ((z > 0.f) ? z : 0.2f * z) * att4.w;
#pragma unroll
            for (int sh = 8; sh >= 1; sh >>= 1) {  // 16-lane reduce
                c0 += __shfl_xor(c0, sh);
                c1 += __shfl_xor(c1, sh);
            }
            float w0 = aa ? __expf(fminf(c0, 30.f)) : 0.f;
            float w1 = ab ? __expf(fminf(c1, 30.f)) : 0.f;
            s += w0 + w1;
            acc.x += w0 * x0.x + w1 * x1.x;
            acc.y += w0 * x0.y + w1 * x1.y;
            acc.z += w0 * x0.z + w1 * x1.z;
            acc.w += w0 * x0.w + w1 * x1.w;
        }
        // overflow fold (deg > ELLC): empty in practice
        if (deg_d > ELLC) {
            int no = min(*novf, OVF_CAP);
            for (int j = g; j < no; j += 4) {
                bool active = (ovf_dst[j] == d);
                int  i0     = active ? ovf_src[j] : i_first;
                half4 h0 = ((const half4*)(xl + (size_t)i0 * 64))[l];
                float4 x0 = make_float4((float)h0[0], (float)h0[1], (float)h0[2], (float)h0[3]);
                float z, c0 = 0.f;
                z = x0.x + xr4.x; c0 += ((z > 0.f) ? z : 0.2f * z) * att4.x;
                z = x0.y + xr4.y; c0 += ((z > 0.f) ? z : 0.2f * z) * att4.y;
                z = x0.z + xr4.z; c0 += ((z > 0.f) ? z : 0.2f * z) * att4.z;
                z = x0.w + xr4.w; c0 += ((z > 0.f) ? z : 0.2f * z) * att4.w;
#pragma unroll
                for (int sh = 8; sh >= 1; sh >>= 1) c0 += __shfl_xor(c0, sh);
                float w0 = active ? __expf(fminf(c0, 30.f)) : 0.f;
                s += w0;
                acc.x += w0 * x0.x;
                acc.y += w0 * x0.y;
                acc.z += w0 * x0.z;
                acc.w += w0 * x0.w;
            }
        }
        // merge the 4 group partial sums, xor 16 then xor 32
#pragma unroll
        for (int mask = 16; mask <= 32; mask <<= 1) {
            s     += __shfl_xor(s, mask);
            acc.x += __shfl_xor(acc.x, mask);
            acc.y += __shfl_xor(acc.y, mask);
            acc.z += __shfl_xor(acc.z, mask);
            acc.w += __shfl_xor(acc.w, mask);
        }
    }
    if (g == 0) {
        float inv = (s > 0.f) ? (1.f / s) : 0.f;   // deg-0 -> relu(bias)
        half4 hv;
        hv[0] = (_Float16)fmaxf(acc.x * inv + b4.x, 0.f);
        hv[1] = (_Float16)fmaxf(acc.y * inv + b4.y, 0.f);
        hv[2] = (_Float16)fmaxf(acc.z * inv + b4.z, 0.f);
        hv[3] = (_Float16)fmaxf(acc.w * inv + b4.w, 0.f);
        ((half4*)(out + (size_t)d * 64))[l] = hv;
    }
}

// ---------------- per-graph mean pool + final linear (no atomics) ---------
// block g = graph g; batch is sorted -> binary search node range.
__global__ __launch_bounds__(256) void pool_final_kernel(
    const _Float16* __restrict__ h, const int* __restrict__ batch,
    const float* __restrict__ lin_w, const float* __restrict__ lin_b,
    float* __restrict__ out, int N, int G) {
    int g = blockIdx.x;
    int t = threadIdx.x;
    // lower_bound(batch, key)
    auto lb = [&](int key) {
        int lo = 0, hi = N;
        while (lo < hi) {
            int mid = (lo + hi) >> 1;
            if (batch[mid] < key) lo = mid + 1; else hi = mid;
        }
        return lo;
    };
    int start = lb(g), end = lb(g + 1);

    __shared__ float part[4][64];
    __shared__ float pooled[64];
    int f = t & 63, w = t >> 6;
    float acc = 0.f;
    for (int i = start + w; i < end; i += 4)          // ~25 rows/thread
        acc += (float)h[(size_t)i * 64 + f];
    part[w][f] = acc;
    __syncthreads();
    if (t < 64) {
        float s = part[0][t] + part[1][t] + part[2][t] + part[3][t];
        pooled[t] = s / fmaxf((float)(end - start), 1.f);
    }
    __syncthreads();
    if (t < 32) {
        float a = 0.f;
#pragma unroll 8
        for (int hh = 0; hh < 64; ++hh) a += pooled[hh] * lin_w[hh * 32 + t];
        out[g * 32 + t] = a + lin_b[t];
    }
}

extern "C" void kernel_launch(void* const* d_in, const int* in_sizes, int n_in,
                              void* d_out, int out_size, void* d_ws, size_t ws_size,
                              hipStream_t stream) {
    const float* x     = (const float*)d_in[0];
    const int*   ei    = (const int*)d_in[1];
    const int*   batch = (const int*)d_in[2];
    const float* Wl1   = (const float*)d_in[3];
    const float* bl1   = (const float*)d_in[4];
    const float* Wr1   = (const float*)d_in[5];
    const float* br1   = (const float*)d_in[6];
    const float* att1  = (const float*)d_in[7];
    const float* bias1 = (const float*)d_in[8];
    const float* Wl2   = (const float*)d_in[9];
    const float* bl2   = (const float*)d_in[10];
    const float* Wr2   = (const float*)d_in[11];
    const float* br2   = (const float*)d_in[12];
    const float* att2  = (const float*)d_in[13];
    const float* bias2 = (const float*)d_in[14];
    const float* lin_w = (const float*)d_in[15];
    const float* lin_b = (const float*)d_in[16];
    float* out = (float*)d_out;

    const int N = in_sizes[0] / 64;
    const int E = in_sizes[1] / 2;
    const int G = out_size / 32;
    const int* src = ei;
    const int* dst = ei + E;

    // ---- workspace carve-up (256B-aligned) ----
    char*  ws  = (char*)d_ws;
    size_t off = 0;
    auto alloc = [&](size_t bytes) -> void* {
        void* p = ws + off;
        off += bytes;
        off = (off + 255) & ~(size_t)255;
        return p;
    };
    _Float16* xl   = (_Float16*)alloc((size_t)N * 64 * sizeof(_Float16));
    float* xr      = (float*)alloc((size_t)N * 64 * sizeof(float));
    _Float16* h1   = (_Float16*)alloc((size_t)N * 64 * sizeof(_Float16));  // h1/h2
    // zeroed region (contiguous): cnt, novf
    int*   cnt     = (int*)alloc((size_t)N * sizeof(int));
    int*   novf    = (int*)alloc(256);
    char*  zend    = ws + off;
    unsigned short* ell = (unsigned short*)alloc((size_t)N * ELLC * sizeof(unsigned short));
    int*   ovf_dst = (int*)alloc((size_t)OVF_CAP * sizeof(int));
    int*   ovf_src = (int*)alloc((size_t)OVF_CAP * sizeof(int));

    (void)hipMemsetAsync(cnt, 0, (size_t)(zend - (char*)cnt), stream);

    int ggrid  = (N + GROWS - 1) / GROWS;
    int agrid  = (N + 3) / 4;                    // one wave per dst node
    int nchunk = (E + ECHUNK - 1) / ECHUNK;
    int fb     = nchunk * 8;                     // fill virtual blocks (x8 XCD)
    int psize  = (N + 7) / 8;                    // dst partition size
    // interleaved grid: groups of 24 = 16 fill + 8 gemm
    int ngroups = max((fb + 15) / 16, (ggrid + 7) / 8);
    int igrid   = ngroups * 24;

    // ---- interleaved: XCD-partitioned ELL fill + layer-1 dual GEMM ----
    fill_gemm_kernel<<<igrid, 256, 0, stream>>>(
        src, dst, cnt, ell, novf, ovf_dst, ovf_src, E, N, psize, fb, ggrid,
        x, Wl1, bl1, Wr1, br1, xl, xr);

    // ---- agg1 -> h1 (fp16) ----
    gat_aggregate_kernel<<<agrid, 256, 0, stream>>>(
        xl, xr, cnt, ell, novf, ovf_dst, ovf_src, att1, bias1, h1, N);

    // ---- layer 2 GEMM (fp16 input; h1 consumed, xl/xr overwritten) ----
    dual_gemm64_f16_kernel<<<ggrid, 256, 0, stream>>>(
        h1, Wl2, bl2, Wr2, br2, xl, xr, N);

    // ---- agg2 -> h1 (fp16, reused) ----
    gat_aggregate_kernel<<<agrid, 256, 0, stream>>>(
        xl, xr, cnt, ell, novf, ovf_dst, ovf_src, att2, bias2, h1, N);

    // ---- per-graph pool + final linear (one dispatch, no atomics) ----
    pool_final_kernel<<<G, 256, 0, stream>>>(h1, batch, lin_w, lin_b, out, N, G);
}